// Round 10
// baseline (48.613 us; speedup 1.0000x reference)
//
#include <hip/hip_runtime.h>

#define IMG_W 1024
#define IMG_H 1024

typedef float f32x4 __attribute__((ext_vector_type(4)));

// One block (512 threads, 8 waves) per QUAD of horizontally-adjacent 128x128
// tiles. 512 blocks = 2 blocks/CU (16 waves/CU). 4-stage software pipeline:
// store(i-1) overlaps read(i). NT policy: input read nontemporally (used once,
// don't pollute L3); output stored NORMALLY so the 134 MB output lives in the
// 256 MB Infinity Cache and steady-state replays never write it back to HBM.
__global__ __launch_bounds__(512, 4) void clahe_kernel(const float* __restrict__ img,
                                                       float* __restrict__ out) {
    const int quad = blockIdx.x;          // 0..511
    const int t0 = quad << 2;             // first tile of the quad
    const int b  = t0 >> 6;
    const int ty = (t0 >> 3) & 7;
    const int tx = t0 & 7;                // 0 or 4

    const size_t base0 = ((size_t)b * IMG_H + (size_t)ty * 128) * IMG_W + (size_t)tx * 128;

    const int t = threadIdx.x;            // 0..511
    const int w = t >> 6;                 // wave id 0..7

    __shared__ int   hist[8][256];        // 8 KB
    __shared__ float cdf[2][256];         // 2 KB ping-pong
    __shared__ float exw[4];
    __shared__ float wsum[4];

    int* hflat = &hist[0][0];
    hflat[t] = 0; hflat[t + 512] = 0; hflat[t + 1024] = 0; hflat[t + 1536] = 0;
    __syncthreads();

    // thread's element j of a tile: row = (t>>5) + 16*j, col = (t&31)*4
    const size_t toff = (size_t)(t >> 5) * IMG_W + ((t & 31) << 2);
    const float* __restrict__ p0 = img + base0 + toff;
    float* __restrict__ d0 = out + base0 + toff;

    unsigned int pk[2][8];                // ping-pong packed 255-indices
    f32x4 v[8];

    auto binpack = [&](const f32x4 vv, unsigned int* pkp) {
        atomicAdd(&hist[w][min(255, (int)(vv.x * 256.0f))], 1);
        atomicAdd(&hist[w][min(255, (int)(vv.y * 256.0f))], 1);
        atomicAdd(&hist[w][min(255, (int)(vv.z * 256.0f))], 1);
        atomicAdd(&hist[w][min(255, (int)(vv.w * 256.0f))], 1);
        *pkp = (unsigned int)min(255, (int)(vv.x * 255.0f))
             | ((unsigned int)min(255, (int)(vv.y * 255.0f)) << 8)
             | ((unsigned int)min(255, (int)(vv.z * 255.0f)) << 16)
             | ((unsigned int)min(255, (int)(vv.w * 255.0f)) << 24);
    };

    // clip + scan -> cdf[s]; zeroes hist for the next tile. One internal barrier;
    // caller barriers after before consuming cdf[s].
    auto scan_fn = [&](int s) {
        int h = 0;
        float x = 0.0f;
        if (t < 256) {
            h = hist[0][t] + hist[1][t] + hist[2][t] + hist[3][t]
              + hist[4][t] + hist[5][t] + hist[6][t] + hist[7][t];

            float ex = (float)max(h - 128, 0);
            #pragma unroll
            for (int off = 32; off > 0; off >>= 1) ex += __shfl_xor(ex, off);
            if ((t & 63) == 0) exw[w] = ex;

            x = fminf((float)h, 128.0f);
            #pragma unroll
            for (int off = 1; off < 64; off <<= 1) {
                const float y = __shfl_up(x, off);
                if ((t & 63) >= off) x += y;
            }
            if ((t & 63) == 63) wsum[w] = x;
        }
        __syncthreads();
        // zero hist for next tile (reads of hist completed above)
        hflat[t] = 0; hflat[t + 512] = 0; hflat[t + 1024] = 0; hflat[t + 1536] = 0;
        if (t < 256) {
            const float excess = exw[0] + exw[1] + exw[2] + exw[3];
            float prefix = 0.0f;
            if (w > 0) prefix += wsum[0];
            if (w > 1) prefix += wsum[1];
            if (w > 2) prefix += wsum[2];
            const float summinh = wsum[0] + wsum[1] + wsum[2] + wsum[3];
            const float e256 = excess * (1.0f / 256.0f);
            const float total = summinh + excess;
            cdf[s][t] = (x + prefix + (float)(t + 1) * e256) / total;
        }
    };

    #pragma unroll
    for (int i = 0; i < 4; ++i) {
        const float* pi = p0 + (size_t)i * 128;
        // issue this tile's 8 loads first (MLP), then overlap prev-tile store
        #pragma unroll
        for (int j = 0; j < 8; ++j)
            v[j] = __builtin_nontemporal_load(
                reinterpret_cast<const f32x4*>(pi + (size_t)j * 16 * IMG_W));

        if (i > 0) {
            float* dprev = d0 + (size_t)(i - 1) * 128;
            #pragma unroll
            for (int j = 0; j < 8; ++j) {
                const unsigned int u = pk[(i - 1) & 1][j];
                f32x4 o;
                o.x = cdf[(i - 1) & 1][u & 255u];
                o.y = cdf[(i - 1) & 1][(u >> 8) & 255u];
                o.z = cdf[(i - 1) & 1][(u >> 16) & 255u];
                o.w = cdf[(i - 1) & 1][u >> 24];
                *reinterpret_cast<f32x4*>(dprev + (size_t)j * 16 * IMG_W) = o;
            }
        }

        #pragma unroll
        for (int j = 0; j < 8; ++j) binpack(v[j], &pk[i & 1][j]);
        __syncthreads();

        scan_fn(i & 1);
        __syncthreads();
    }

    // epilogue: store tile 3
    {
        float* dprev = d0 + (size_t)3 * 128;
        #pragma unroll
        for (int j = 0; j < 8; ++j) {
            const unsigned int u = pk[1][j];
            f32x4 o;
            o.x = cdf[1][u & 255u];
            o.y = cdf[1][(u >> 8) & 255u];
            o.z = cdf[1][(u >> 16) & 255u];
            o.w = cdf[1][u >> 24];
            *reinterpret_cast<f32x4*>(dprev + (size_t)j * 16 * IMG_W) = o;
        }
    }
}

extern "C" void kernel_launch(void* const* d_in, const int* in_sizes, int n_in,
                              void* d_out, int out_size, void* d_ws, size_t ws_size,
                              hipStream_t stream) {
    const float* img = (const float*)d_in[0];
    float* out = (float*)d_out;
    clahe_kernel<<<512, 512, 0, stream>>>(img, out);
}

// Round 11
// 44.212 us; speedup vs baseline: 1.0995x; 1.0995x over previous
//
#include <hip/hip_runtime.h>

#define IMG_W 1024
#define IMG_H 1024

typedef float f32x4 __attribute__((ext_vector_type(4)));

// One block (512 threads, 8 waves) per QUAD of horizontally-adjacent 128x128
// tiles. 512 blocks = 2 blocks/CU (16 waves/CU). 4-stage software pipeline:
// store(i-1) overlaps read(i); only first read and last store are exposed.
// Policy (validated R9/R10): plain loads (input half-rides L3 -> 65 MB fetch),
// NT stores (output bypasses L3, doesn't evict input).
__global__ __launch_bounds__(512, 4) void clahe_kernel(const float* __restrict__ img,
                                                       float* __restrict__ out) {
    const int quad = blockIdx.x;          // 0..511
    const int t0 = quad << 2;             // first tile of the quad
    const int b  = t0 >> 6;
    const int ty = (t0 >> 3) & 7;
    const int tx = t0 & 7;                // 0 or 4

    const size_t base0 = ((size_t)b * IMG_H + (size_t)ty * 128) * IMG_W + (size_t)tx * 128;

    const int t = threadIdx.x;            // 0..511
    const int w = t >> 6;                 // wave id 0..7

    __shared__ int   hist[8][256];        // 8 KB
    __shared__ float cdf[2][256];         // 2 KB ping-pong
    __shared__ float exw[4];
    __shared__ float wsum[4];

    int* hflat = &hist[0][0];
    hflat[t] = 0; hflat[t + 512] = 0; hflat[t + 1024] = 0; hflat[t + 1536] = 0;
    __syncthreads();

    // thread's element j of a tile: f = t + j*512 -> row = (t>>5) + 16*j, col = (t&31)*4
    const size_t toff = (size_t)(t >> 5) * IMG_W + ((t & 31) << 2);
    const float* __restrict__ p0 = img + base0 + toff;
    float* __restrict__ d0 = out + base0 + toff;

    unsigned int pk[2][8];                // ping-pong packed 255-indices
    f32x4 v[8];

    auto binpack = [&](const f32x4 vv, unsigned int* pkp) {
        atomicAdd(&hist[w][min(255, (int)(vv.x * 256.0f))], 1);
        atomicAdd(&hist[w][min(255, (int)(vv.y * 256.0f))], 1);
        atomicAdd(&hist[w][min(255, (int)(vv.z * 256.0f))], 1);
        atomicAdd(&hist[w][min(255, (int)(vv.w * 256.0f))], 1);
        *pkp = (unsigned int)min(255, (int)(vv.x * 255.0f))
             | ((unsigned int)min(255, (int)(vv.y * 255.0f)) << 8)
             | ((unsigned int)min(255, (int)(vv.z * 255.0f)) << 16)
             | ((unsigned int)min(255, (int)(vv.w * 255.0f)) << 24);
    };

    // clip + scan -> cdf[s]; zeroes hist for the next tile. One internal barrier;
    // caller barriers after before consuming cdf[s].
    auto scan_fn = [&](int s) {
        int h = 0;
        float x = 0.0f;
        if (t < 256) {
            h = hist[0][t] + hist[1][t] + hist[2][t] + hist[3][t]
              + hist[4][t] + hist[5][t] + hist[6][t] + hist[7][t];

            float ex = (float)max(h - 128, 0);
            #pragma unroll
            for (int off = 32; off > 0; off >>= 1) ex += __shfl_xor(ex, off);
            if ((t & 63) == 0) exw[w] = ex;

            x = fminf((float)h, 128.0f);
            #pragma unroll
            for (int off = 1; off < 64; off <<= 1) {
                const float y = __shfl_up(x, off);
                if ((t & 63) >= off) x += y;
            }
            if ((t & 63) == 63) wsum[w] = x;
        }
        __syncthreads();
        // zero hist for next tile (reads of hist completed above)
        hflat[t] = 0; hflat[t + 512] = 0; hflat[t + 1024] = 0; hflat[t + 1536] = 0;
        if (t < 256) {
            const float excess = exw[0] + exw[1] + exw[2] + exw[3];
            float prefix = 0.0f;
            if (w > 0) prefix += wsum[0];
            if (w > 1) prefix += wsum[1];
            if (w > 2) prefix += wsum[2];
            const float summinh = wsum[0] + wsum[1] + wsum[2] + wsum[3];
            const float e256 = excess * (1.0f / 256.0f);
            const float total = summinh + excess;
            cdf[s][t] = (x + prefix + (float)(t + 1) * e256) / total;
        }
    };

    #pragma unroll
    for (int i = 0; i < 4; ++i) {
        const float* pi = p0 + (size_t)i * 128;
        // issue this tile's 8 loads first (MLP), then overlap prev-tile store
        #pragma unroll
        for (int j = 0; j < 8; ++j)
            v[j] = *reinterpret_cast<const f32x4*>(pi + (size_t)j * 16 * IMG_W);

        if (i > 0) {
            float* dprev = d0 + (size_t)(i - 1) * 128;
            #pragma unroll
            for (int j = 0; j < 8; ++j) {
                const unsigned int u = pk[(i - 1) & 1][j];
                f32x4 o;
                o.x = cdf[(i - 1) & 1][u & 255u];
                o.y = cdf[(i - 1) & 1][(u >> 8) & 255u];
                o.z = cdf[(i - 1) & 1][(u >> 16) & 255u];
                o.w = cdf[(i - 1) & 1][u >> 24];
                __builtin_nontemporal_store(
                    o, reinterpret_cast<f32x4*>(dprev + (size_t)j * 16 * IMG_W));
            }
        }

        #pragma unroll
        for (int j = 0; j < 8; ++j) binpack(v[j], &pk[i & 1][j]);
        __syncthreads();

        scan_fn(i & 1);
        __syncthreads();
    }

    // epilogue: store tile 3
    {
        float* dprev = d0 + (size_t)3 * 128;
        #pragma unroll
        for (int j = 0; j < 8; ++j) {
            const unsigned int u = pk[1][j];
            f32x4 o;
            o.x = cdf[1][u & 255u];
            o.y = cdf[1][(u >> 8) & 255u];
            o.z = cdf[1][(u >> 16) & 255u];
            o.w = cdf[1][u >> 24];
            __builtin_nontemporal_store(
                o, reinterpret_cast<f32x4*>(dprev + (size_t)j * 16 * IMG_W));
        }
    }
}

extern "C" void kernel_launch(void* const* d_in, const int* in_sizes, int n_in,
                              void* d_out, int out_size, void* d_ws, size_t ws_size,
                              hipStream_t stream) {
    const float* img = (const float*)d_in[0];
    float* out = (float*)d_out;
    clahe_kernel<<<512, 512, 0, stream>>>(img, out);
}

// Round 12
// 44.183 us; speedup vs baseline: 1.1003x; 1.0007x over previous
//
#include <hip/hip_runtime.h>

#define IMG_W 1024
#define IMG_H 1024

typedef float f32x4 __attribute__((ext_vector_type(4)));

// Barrier that drains ONLY LDS (lgkmcnt), not vmem: NT stores keep flying
// across it. __syncthreads() would emit s_waitcnt vmcnt(0) before s_barrier,
// forcing a wait on NT-store completion to HBM at every barrier (12/block).
// Cross-wave deps in this kernel are exclusively through LDS -> lgkm-only
// is sufficient. sched_barrier(0) pins LDS reads below the barrier (rule #18).
__device__ __forceinline__ void lgkm_barrier() {
    asm volatile("s_waitcnt lgkmcnt(0)" ::: "memory");
    __builtin_amdgcn_s_barrier();
    __builtin_amdgcn_sched_barrier(0);
}

// One block (512 threads, 8 waves) per QUAD of horizontally-adjacent 128x128
// tiles. 512 blocks = 2 blocks/CU (16 waves/CU). 4-stage software pipeline:
// store(i-1) overlaps read(i). Plain loads (input half-rides L3), NT stores.
__global__ __launch_bounds__(512, 4) void clahe_kernel(const float* __restrict__ img,
                                                       float* __restrict__ out) {
    const int quad = blockIdx.x;          // 0..511
    const int t0 = quad << 2;             // first tile of the quad
    const int b  = t0 >> 6;
    const int ty = (t0 >> 3) & 7;
    const int tx = t0 & 7;                // 0 or 4

    const size_t base0 = ((size_t)b * IMG_H + (size_t)ty * 128) * IMG_W + (size_t)tx * 128;

    const int t = threadIdx.x;            // 0..511
    const int w = t >> 6;                 // wave id 0..7

    __shared__ int   hist[8][256];        // 8 KB
    __shared__ float cdf[2][256];         // 2 KB ping-pong
    __shared__ float exw[4];
    __shared__ float wsum[4];

    int* hflat = &hist[0][0];
    hflat[t] = 0; hflat[t + 512] = 0; hflat[t + 1024] = 0; hflat[t + 1536] = 0;
    lgkm_barrier();

    // thread's element j of a tile: row = (t>>5) + 16*j, col = (t&31)*4
    const size_t toff = (size_t)(t >> 5) * IMG_W + ((t & 31) << 2);
    const float* __restrict__ p0 = img + base0 + toff;
    float* __restrict__ d0 = out + base0 + toff;

    unsigned int pk[2][8];                // ping-pong packed 255-indices
    f32x4 v[8];

    auto binpack = [&](const f32x4 vv, unsigned int* pkp) {
        atomicAdd(&hist[w][min(255, (int)(vv.x * 256.0f))], 1);
        atomicAdd(&hist[w][min(255, (int)(vv.y * 256.0f))], 1);
        atomicAdd(&hist[w][min(255, (int)(vv.z * 256.0f))], 1);
        atomicAdd(&hist[w][min(255, (int)(vv.w * 256.0f))], 1);
        *pkp = (unsigned int)min(255, (int)(vv.x * 255.0f))
             | ((unsigned int)min(255, (int)(vv.y * 255.0f)) << 8)
             | ((unsigned int)min(255, (int)(vv.z * 255.0f)) << 16)
             | ((unsigned int)min(255, (int)(vv.w * 255.0f)) << 24);
    };

    // clip + scan -> cdf[s]; zeroes hist for the next tile. One internal
    // lgkm-barrier; caller barriers after before consuming cdf[s].
    auto scan_fn = [&](int s) {
        int h = 0;
        float x = 0.0f;
        if (t < 256) {
            h = hist[0][t] + hist[1][t] + hist[2][t] + hist[3][t]
              + hist[4][t] + hist[5][t] + hist[6][t] + hist[7][t];

            float ex = (float)max(h - 128, 0);
            #pragma unroll
            for (int off = 32; off > 0; off >>= 1) ex += __shfl_xor(ex, off);
            if ((t & 63) == 0) exw[w] = ex;

            x = fminf((float)h, 128.0f);
            #pragma unroll
            for (int off = 1; off < 64; off <<= 1) {
                const float y = __shfl_up(x, off);
                if ((t & 63) >= off) x += y;
            }
            if ((t & 63) == 63) wsum[w] = x;
        }
        lgkm_barrier();
        // zero hist for next tile (reads of hist completed above)
        hflat[t] = 0; hflat[t + 512] = 0; hflat[t + 1024] = 0; hflat[t + 1536] = 0;
        if (t < 256) {
            const float excess = exw[0] + exw[1] + exw[2] + exw[3];
            float prefix = 0.0f;
            if (w > 0) prefix += wsum[0];
            if (w > 1) prefix += wsum[1];
            if (w > 2) prefix += wsum[2];
            const float summinh = wsum[0] + wsum[1] + wsum[2] + wsum[3];
            const float e256 = excess * (1.0f / 256.0f);
            const float total = summinh + excess;
            cdf[s][t] = (x + prefix + (float)(t + 1) * e256) / total;
        }
    };

    #pragma unroll
    for (int i = 0; i < 4; ++i) {
        const float* pi = p0 + (size_t)i * 128;
        // issue this tile's 8 loads first (MLP), then overlap prev-tile store
        #pragma unroll
        for (int j = 0; j < 8; ++j)
            v[j] = *reinterpret_cast<const f32x4*>(pi + (size_t)j * 16 * IMG_W);

        if (i > 0) {
            float* dprev = d0 + (size_t)(i - 1) * 128;
            #pragma unroll
            for (int j = 0; j < 8; ++j) {
                const unsigned int u = pk[(i - 1) & 1][j];
                f32x4 o;
                o.x = cdf[(i - 1) & 1][u & 255u];
                o.y = cdf[(i - 1) & 1][(u >> 8) & 255u];
                o.z = cdf[(i - 1) & 1][(u >> 16) & 255u];
                o.w = cdf[(i - 1) & 1][u >> 24];
                __builtin_nontemporal_store(
                    o, reinterpret_cast<f32x4*>(dprev + (size_t)j * 16 * IMG_W));
            }
        }

        #pragma unroll
        for (int j = 0; j < 8; ++j) binpack(v[j], &pk[i & 1][j]);
        lgkm_barrier();

        scan_fn(i & 1);
        lgkm_barrier();
    }

    // epilogue: store tile 3
    {
        float* dprev = d0 + (size_t)3 * 128;
        #pragma unroll
        for (int j = 0; j < 8; ++j) {
            const unsigned int u = pk[1][j];
            f32x4 o;
            o.x = cdf[1][u & 255u];
            o.y = cdf[1][(u >> 8) & 255u];
            o.z = cdf[1][(u >> 16) & 255u];
            o.w = cdf[1][u >> 24];
            __builtin_nontemporal_store(
                o, reinterpret_cast<f32x4*>(dprev + (size_t)j * 16 * IMG_W));
        }
    }
}

extern "C" void kernel_launch(void* const* d_in, const int* in_sizes, int n_in,
                              void* d_out, int out_size, void* d_ws, size_t ws_size,
                              hipStream_t stream) {
    const float* img = (const float*)d_in[0];
    float* out = (float*)d_out;
    clahe_kernel<<<512, 512, 0, stream>>>(img, out);
}